// Round 6
// baseline (200.245 us; speedup 1.0000x reference)
//
#include <hip/hip_runtime.h>
#include <math.h>

#define N_PTS   8192
#define KNN     30
#define CAPG    104     // max stored candidates per group
#define STR     105     // LDS row stride in u64
#define GROUPS  8       // queries per block
#define BLOCK   128     // 2 waves per block
#define NZ      64
#define NY      64
#define NBKT    (NZ * NY)
#define CLO     -4.0f
#define CSC     8.0f    // buckets per unit: bucket = floor((c - CLO) * CSC)
#define INVCSC  0.125f
#define LAMBDA  40.0f   // target in-ball count (rank work ~ cnt^2)
#define RBINS   2048    // radius-table bins over qp.w
#define RWMAX   32.0f   // table domain [0, 32) for |q|^2
#define RSCALE  ((float)RBINS / RWMAX)

// ws: S f4[32768]@0 | O i32[32768]@524288 | bstart i32[4*4097]@655360 |
//     R2T f32[2048]@720912  (total 728 KB)

__device__ __forceinline__ int clampi(int v, int lo, int hi) {
    return v < lo ? lo : (v > hi ? hi : v);
}
__device__ __forceinline__ int bucket_of(float pz, float py) {
    int zb = clampi((int)floorf((pz - CLO) * CSC), 0, NZ - 1);
    int yb = clampi((int)floorf((py - CLO) * CSC), 0, NY - 1);
    return (zb << 6) | yb;
}

// ---------------------------------------------------------------------------
// Fused prep: blocks 0..3 = one batch each (1024 threads): LDS hist ->
// in-block scan -> counting-sort scatter; copies x into out ch0..2.
// Block 4 ONLY builds the radius table (input-independent), overlapping the
// batch blocks -> table is off the critical path (r5 lesson: it cost ~30 us
// when serialized after block 0's scatter).
// ---------------------------------------------------------------------------
__global__ __launch_bounds__(1024) void prep_kernel(const float* __restrict__ x,
                                                    float4* __restrict__ S,
                                                    int* __restrict__ O,
                                                    int* __restrict__ bstart,
                                                    float* __restrict__ R2T,
                                                    float* __restrict__ out) {
    __shared__ int hist[NBKT];    // 16 KB
    __shared__ int cur[NBKT];     // 16 KB (bucket cursors)
    __shared__ int wsum[16];

    const int b = blockIdx.x;
    const int t = threadIdx.x;

    if (b == 4) {
        // ---- radius table: solve lambda(r)=LAMBDA per w-bin (Simpson-9) ----
        for (int k = t; k < RBINS; k += 1024) {
            float wrep = ((float)k + 0.5f) * (RWMAX / (float)RBINS);
            float c = fmaxf(sqrtf(wrep), 1e-3f);
            float rlo = 0.05f, rhi = 6.0f;
            for (int it = 0; it < 20; ++it) {
                float r = 0.5f * (rlo + rhi);
                float slo = fmaxf(c - r, 0.0f);
                float h = (c + r - slo) * 0.125f;
                float f = 0.0f;
                #pragma unroll
                for (int l = 0; l <= 8; ++l) {
                    float sq = slo + h * (float)l;
                    float cs = c - sq;
                    float hh = fmaxf(fminf((r * r - cs * cs) * (0.5f / c), 2.0f * sq), 0.0f);
                    float wq = (l == 0 || l == 8) ? 1.0f : ((l & 1) ? 4.0f : 2.0f);
                    f += wq * __expf(-0.5f * sq * sq) * sq * hh;
                }
                float lam = 1089.3f * f * h;       // 520.1 * 2*pi / 3
                if (lam < LAMBDA) rlo = r; else rhi = r;
            }
            float rad = rhi * 1.02f;
            R2T[k] = rad * rad;
        }
        return;
    }

    const int wid = t >> 6, lane = t & 63;
    const float* xb = x + (size_t)b * 3 * N_PTS;
    float* ob = out + (size_t)b * 6 * N_PTS;

    for (int k = t; k < NBKT; k += 1024) hist[k] = 0;
    __syncthreads();

    float px[8], py[8], pz[8];
    int   bk[8];
    #pragma unroll
    for (int u = 0; u < 8; ++u) {
        int i = (u << 10) + t;
        px[u] = xb[i]; py[u] = xb[N_PTS + i]; pz[u] = xb[2 * N_PTS + i];
        bk[u] = bucket_of(pz[u], py[u]);
        atomicAdd(&hist[bk[u]], 1);
        ob[i]             = px[u];
        ob[N_PTS + i]     = py[u];
        ob[2 * N_PTS + i] = pz[u];
    }
    __syncthreads();

    // block scan: thread t owns buckets 4t..4t+3
    int l0 = hist[4 * t], l1 = hist[4 * t + 1], l2 = hist[4 * t + 2], l3 = hist[4 * t + 3];
    int s = l0 + l1 + l2 + l3;
    int sum = s;
    #pragma unroll
    for (int off = 1; off < 64; off <<= 1) {
        int v = __shfl_up(sum, off);
        if (lane >= off) sum += v;
    }
    if (lane == 63) wsum[wid] = sum;
    __syncthreads();
    if (t == 0) {
        int run = 0;
        #pragma unroll
        for (int k = 0; k < 16; ++k) { int v = wsum[k]; wsum[k] = run; run += v; }
    }
    __syncthreads();
    int base = wsum[wid] + (sum - s);     // exclusive prefix for this thread
    int b0 = base, b1 = base + l0, b2 = b1 + l1, b3 = b2 + l2;
    cur[4 * t] = b0; cur[4 * t + 1] = b1; cur[4 * t + 2] = b2; cur[4 * t + 3] = b3;
    int* bsb = bstart + b * (NBKT + 1);
    bsb[4 * t] = b0; bsb[4 * t + 1] = b1; bsb[4 * t + 2] = b2; bsb[4 * t + 3] = b3;
    if (t == 1023) bsb[NBKT] = N_PTS;
    __syncthreads();

    // scatter (xx_np = bitwise-numpy |p|^2, no fma)
    float4* Sb = S + ((size_t)b << 13);
    int*    Ob = O + ((size_t)b << 13);
    #pragma unroll
    for (int u = 0; u < 8; ++u) {
        int dst = atomicAdd(&cur[bk[u]], 1);
        float xx = __fadd_rn(__fadd_rn(__fmul_rn(px[u], px[u]), __fmul_rn(py[u], py[u])),
                             __fmul_rn(pz[u], pz[u]));
        Sb[dst] = make_float4(px[u], py[u], pz[u], xx);
        Ob[dst] = (u << 10) + t;
    }
}

// ---------------------------------------------------------------------------
// Main. Scan phase: WAVE-COOPERATIVE — the wave's 4 queries are processed
// sequentially at 64-lane width (128 cand/iter), so wave scan time is
// sum/4 rather than max over 4 groups (removes intra-wave imbalance; a heavy
// query no longer idles 48 lanes). Retries are per-query and wave-uniform.
// Fill/rank/epilogue: 16 lanes per query as before. Candidate SET per query
// is identical to the group-parallel version -> same top-30 selection.
// ---------------------------------------------------------------------------
__global__ __launch_bounds__(BLOCK, 6) void knn_normal_kernel(const float4* __restrict__ S,
                                                              const int* __restrict__ O,
                                                              const int* __restrict__ bstart,
                                                              const float* __restrict__ R2T,
                                                              float* __restrict__ out) {
    __shared__ unsigned long long ldk[GROUPS * STR];

    const int t    = threadIdx.x;
    const int lane = t & 63;
    const int wv   = t >> 6;
    const int l16  = t & 15;
    const int g    = t >> 4;          // 0..7: group within block
    const int gw   = g & 3;           // group within wave
    const int qblk = (blockIdx.x * 1031) & 4095;   // bijective swizzle
    const int qid  = qblk * GROUPS + g;
    const int b    = qid >> 13;
    const int pos  = qid & (N_PTS - 1);
    const float4* __restrict__ P  = S + ((size_t)b << 13);
    const int*    __restrict__ Ob = O + ((size_t)b << 13);
    const float4 qp = P[pos];
    const int    oi = Ob[pos];

    unsigned long long* __restrict__ ldg = ldk + g * STR;

    // ---- 64-wide scan, 4 queries sequential per wave ----
    int cnts[4];
    #pragma unroll
    for (int sub = 0; sub < 4; ++sub) {
        const int qs_id  = qblk * GROUPS + (wv << 2) + sub;
        const int bs_    = qs_id >> 13;
        const int pos_s  = qs_id & (N_PTS - 1);
        const float4* __restrict__ Ps  = S + ((size_t)bs_ << 13);
        const int*    __restrict__ bss = bstart + bs_ * (NBKT + 1);
        const float4 qs = Ps[pos_s];
        const int rb = min((int)(qs.w * RSCALE), RBINS - 1);
        float r2s = R2T[rb];
        unsigned long long* __restrict__ row = ldk + ((wv << 2) + sub) * STR;

        int cnt;
        for (;;) {
            cnt = 0;
            float w  = __fmaf_rn(sqrtf(r2s), 1.002f, 1e-3f);   // guard band
            float w2 = __fmul_rn(w, w);
            int zlo = clampi((int)floorf((qs.z - w - CLO) * CSC), 0, NZ - 1);
            int zhi = clampi((int)floorf((qs.z + w - CLO) * CSC), 0, NZ - 1);
            for (int zb = zlo; zb <= zhi; ++zb) {
                // per-row circular y-window (conservative guards; hit set exact)
                float z0  = CLO + (float)zb * INVCSC;
                float dzr = fmaxf(fmaxf(z0 - qs.z, qs.z - (z0 + INVCSC)), 0.0f) * 0.999f;
                float hw2 = __fmaf_rn(-dzr, dzr, w2);
                if (hw2 <= 0.0f) continue;
                float hw  = __fmaf_rn(sqrtf(hw2), 1.001f, 1e-4f);
                int ylo = clampi((int)floorf((qs.y - hw - CLO) * CSC), 0, NY - 1);
                int yhi = clampi((int)floorf((qs.y + hw - CLO) * CSC), 0, NY - 1);
                int lo = bss[(zb << 6) + ylo];
                int hi = bss[(zb << 6) + yhi + 1];
                int smax = (hi - lo + 127) >> 7;   // 128 cand/iter, wave-uniform
                for (int s = 0; s < smax; ++s) {
                    int j1  = lo + (s << 7) + lane;
                    int j2  = j1 + 64;
                    int jc1 = j1 < hi ? j1 : hi - 1;
                    int jc2 = j2 < hi ? j2 : hi - 1;
                    float4 p1 = Ps[jc1];
                    float4 p2 = Ps[jc2];
                    float mm1 = __fmaf_rn(qs.z, p1.z, __fmaf_rn(qs.y, p1.y, __fmul_rn(qs.x, p1.x)));
                    float d1  = __fsub_rn(__fadd_rn(qs.w, p1.w), __fmul_rn(2.0f, mm1));
                    float mm2 = __fmaf_rn(qs.z, p2.z, __fmaf_rn(qs.y, p2.y, __fmul_rn(qs.x, p2.x)));
                    float d2  = __fsub_rn(__fadd_rn(qs.w, p2.w), __fmul_rn(2.0f, mm2));
                    bool hit1 = (j1 < hi) && (d1 <= r2s);
                    bool hit2 = (j2 < hi) && (d2 <= r2s);
                    unsigned long long m1 = __ballot(hit1);
                    if (hit1) {
                        int slot = cnt + __popcll(m1 & ((1ull << lane) - 1ull));
                        if (slot < CAPG) {
                            unsigned u = __float_as_uint(d1);
                            u = (u & 0x80000000u) ? ~u : (u | 0x80000000u);
                            row[slot] = ((unsigned long long)u << 28) | (unsigned long long)jc1;
                        }
                    }
                    cnt += __popcll(m1);
                    unsigned long long m2 = __ballot(hit2);
                    if (hit2) {
                        int slot = cnt + __popcll(m2 & ((1ull << lane) - 1ull));
                        if (slot < CAPG) {
                            unsigned u = __float_as_uint(d2);
                            u = (u & 0x80000000u) ? ~u : (u | 0x80000000u);
                            row[slot] = ((unsigned long long)u << 28) | (unsigned long long)jc2;
                        }
                    }
                    cnt += __popcll(m2);
                }
            }
            if (cnt >= KNN && cnt <= CAPG) break;
            r2s = (cnt < KNN) ? r2s * 1.6f : r2s * 0.82f;
        }
        cnts[sub] = cnt;
    }
    const int cnt = (gw == 0) ? cnts[0] : (gw == 1) ? cnts[1] : (gw == 2) ? cnts[2] : cnts[3];
    __builtin_amdgcn_wave_barrier();
    asm volatile("s_waitcnt lgkmcnt(0)" ::: "memory");

    // fill orig-idx field (bits 14..27) so u64 order == lex (d, orig idx)
    for (int k = l16; k < cnt; k += 16) {
        unsigned long long key = ldg[k];
        int jc = (int)(key & 0x3FFFull);
        ldg[k] = (key & ~0x0FFFFFFFull) | ((unsigned long long)Ob[jc] << 14) | (unsigned long long)jc;
    }
    __builtin_amdgcn_wave_barrier();
    asm volatile("s_waitcnt lgkmcnt(0)" ::: "memory");

    // ---- stable top-30: rank by u64 key (keys unique) ----
    const double qx = (double)qp.x, qy = (double)qp.y, qz = (double)qp.z;
    double sx = 0.0, sy = 0.0, sz = 0.0;
    double sxx = 0.0, sxy = 0.0, sxz = 0.0, syy = 0.0, syz = 0.0, szz = 0.0;

    for (int k = l16; k < cnt; k += 16) {
        unsigned long long key = ldg[k];
        int rank = 0;
        for (int u = 0; u < cnt; ++u) rank += (ldg[u] < key) ? 1 : 0;
        if (rank < KNN) {                         // exactly 30 survivors
            float4 p = P[(int)(key & 0x3FFFull)];
            double ax = (double)p.x - qx, ay = (double)p.y - qy, az = (double)p.z - qz;
            sx += ax; sy += ay; sz += az;
            sxx = fma(ax, ax, sxx); sxy = fma(ax, ay, sxy); sxz = fma(ax, az, sxz);
            syy = fma(ay, ay, syy); syz = fma(ay, az, syz); szz = fma(az, az, szz);
        }
    }

    #pragma unroll
    for (int off = 1; off < 16; off <<= 1) {
        sx  += __shfl_xor(sx,  off, 16); sy  += __shfl_xor(sy,  off, 16); sz  += __shfl_xor(sz,  off, 16);
        sxx += __shfl_xor(sxx, off, 16); sxy += __shfl_xor(sxy, off, 16); sxz += __shfl_xor(sxz, off, 16);
        syy += __shfl_xor(syy, off, 16); syz += __shfl_xor(syz, off, 16); szz += __shfl_xor(szz, off, 16);
    }

    if (l16 == 0) {
        const double kinv = 1.0 / (double)KNN;
        double m00 = sxx - sx * sx * kinv;
        double m11 = syy - sy * sy * kinv;
        double m22 = szz - sz * sz * kinv;
        double m01 = sxy - sx * sy * kinv;
        double m02 = sxz - sx * sz * kinv;
        double m12 = syz - sy * sz * kinv;

        double nx = 1.0, ny = 0.0, nz = 0.0;
        double q3 = (m00 + m11 + m22) / 3.0;
        double p1 = m01 * m01 + m02 * m02 + m12 * m12;
        double d00 = m00 - q3, d11 = m11 - q3, d22 = m22 - q3;
        double p2 = d00 * d00 + d11 * d11 + d22 * d22 + 2.0 * p1;
        if (p2 > 1e-280) {
            double pp = sqrt(p2 / 6.0);
            double ip = 1.0 / pp;
            double b00 = d00 * ip, b11 = d11 * ip, b22 = d22 * ip;
            double b01 = m01 * ip, b02 = m02 * ip, b12 = m12 * ip;
            double detB = b00 * (b11 * b22 - b12 * b12)
                        - b01 * (b01 * b22 - b12 * b02)
                        + b02 * (b01 * b12 - b11 * b02);
            double rr = 0.5 * detB;
            rr = rr < -1.0 ? -1.0 : (rr > 1.0 ? 1.0 : rr);
            double phi = acos(rr) / 3.0;
            double lam = q3 + 2.0 * pp * cos(phi + 2.0943951023931953); // smallest eig
            double a00 = m00 - lam, a11 = m11 - lam, a22 = m22 - lam;
            double v0x = m01 * m12 - m02 * a11, v0y = m02 * m01 - a00 * m12, v0z = a00 * a11 - m01 * m01;
            double v1x = m01 * a22 - m02 * m12, v1y = m02 * m02 - a00 * a22, v1z = a00 * m12 - m01 * m02;
            double v2x = a11 * a22 - m12 * m12, v2y = m12 * m02 - m01 * a22, v2z = m01 * m12 - a11 * m02;
            double n0 = v0x * v0x + v0y * v0y + v0z * v0z;
            double n1 = v1x * v1x + v1y * v1y + v1z * v1z;
            double n2 = v2x * v2x + v2y * v2y + v2z * v2z;
            double bx = v0x, by = v0y, bz = v0z, bn = n0;
            if (n1 > bn) { bx = v1x; by = v1y; bz = v1z; bn = n1; }
            if (n2 > bn) { bx = v2x; by = v2y; bz = v2z; bn = n2; }
            if (bn > 1e-280) {
                double inv = 1.0 / sqrt(bn);
                nx = bx * inv; ny = by * inv; nz = bz * inv;
            }
        }
        double dq = -(qx * nx + qy * ny + qz * nz);
        if (dq < 0.0) { nx = -nx; ny = -ny; nz = -nz; }

        float* ob = out + (size_t)b * 6 * N_PTS;
        ob[3 * N_PTS + oi] = (float)nx;
        ob[4 * N_PTS + oi] = (float)ny;
        ob[5 * N_PTS + oi] = (float)nz;
    }
}

// ---------------------------------------------------------------------------
extern "C" void kernel_launch(void* const* d_in, const int* in_sizes, int n_in,
                              void* d_out, int out_size, void* d_ws, size_t ws_size,
                              hipStream_t stream) {
    const float* x = (const float*)d_in[0];
    float* out = (float*)d_out;
    char* ws = (char*)d_ws;
    float4* S    = (float4*)(ws);                 // 512 KB
    int*    O    = (int*)(ws + 524288);           // 128 KB
    int*    bsta = (int*)(ws + 655360);           // 65552 B
    float*  r2t  = (float*)(ws + 720912);         // 8 KB

    prep_kernel<<<dim3(5), dim3(1024), 0, stream>>>(x, S, O, bsta, r2t, out);
    knn_normal_kernel<<<dim3(32768 / GROUPS), dim3(BLOCK), 0, stream>>>(S, O, bsta, r2t, out);
}

// Round 7
// 156.354 us; speedup vs baseline: 1.2807x; 1.2807x over previous
//
#include <hip/hip_runtime.h>
#include <math.h>

#define N_PTS   8192
#define KNN     30
#define CAPG    104     // max stored candidates per group
#define STR     105     // LDS row stride in u64
#define GROUPS  8       // queries per block
#define BLOCK   128     // 2 waves per block
#define NZ      64
#define NY      64
#define NBKT    (NZ * NY)
#define CLO     -4.0f
#define CSC     8.0f    // buckets per unit: bucket = floor((c - CLO) * CSC)
#define INVCSC  0.125f
#define LAMBDA  40.0    // target in-ball count (rank work ~ cnt^2)
#define RBINS   2048    // radius-table bins over qp.w
#define RWMAX   32.0f   // table domain [0, 32) for |q|^2
#define RSCALE  ((float)RBINS / RWMAX)

// ws: S f4[32768]@0 | O i32[32768]@524288 | bstart i32[4*4097]@655360 |
//     R2T f32[2048]@720912  (total 728 KB)

__device__ __forceinline__ int clampi(int v, int lo, int hi) {
    return v < lo ? lo : (v > hi ? hi : v);
}
__device__ __forceinline__ int bucket_of(float pz, float py) {
    int zb = clampi((int)floorf((pz - CLO) * CSC), 0, NZ - 1);
    int yb = clampi((int)floorf((py - CLO) * CSC), 0, NY - 1);
    return (zb << 6) | yb;
}

// ---------------------------------------------------------------------------
// Fused prep (r4-proven): one block per batch (1024 threads). LDS hist ->
// in-block scan -> LDS-atomic counting-sort scatter. Copies x into out ch0..2.
// NO table build on GPU (r5/r6 lesson: it cost ~28 us wherever it was placed;
// the table is input-independent and now comes from the host via memcpy).
// ---------------------------------------------------------------------------
__global__ __launch_bounds__(1024) void prep_kernel(const float* __restrict__ x,
                                                    float4* __restrict__ S,
                                                    int* __restrict__ O,
                                                    int* __restrict__ bstart,
                                                    float* __restrict__ out) {
    __shared__ int hist[NBKT];    // 16 KB
    __shared__ int cur[NBKT];     // 16 KB (bucket cursors)
    __shared__ int wsum[16];

    const int b = blockIdx.x;
    const int t = threadIdx.x;
    const int wid = t >> 6, lane = t & 63;
    const float* xb = x + (size_t)b * 3 * N_PTS;
    float* ob = out + (size_t)b * 6 * N_PTS;

    for (int k = t; k < NBKT; k += 1024) hist[k] = 0;
    __syncthreads();

    float px[8], py[8], pz[8];
    int   bk[8];
    #pragma unroll
    for (int u = 0; u < 8; ++u) {
        int i = (u << 10) + t;
        px[u] = xb[i]; py[u] = xb[N_PTS + i]; pz[u] = xb[2 * N_PTS + i];
        bk[u] = bucket_of(pz[u], py[u]);
        atomicAdd(&hist[bk[u]], 1);
        ob[i]             = px[u];
        ob[N_PTS + i]     = py[u];
        ob[2 * N_PTS + i] = pz[u];
    }
    __syncthreads();

    // block scan: thread t owns buckets 4t..4t+3
    int l0 = hist[4 * t], l1 = hist[4 * t + 1], l2 = hist[4 * t + 2], l3 = hist[4 * t + 3];
    int s = l0 + l1 + l2 + l3;
    int sum = s;
    #pragma unroll
    for (int off = 1; off < 64; off <<= 1) {
        int v = __shfl_up(sum, off);
        if (lane >= off) sum += v;
    }
    if (lane == 63) wsum[wid] = sum;
    __syncthreads();
    if (t == 0) {
        int run = 0;
        #pragma unroll
        for (int k = 0; k < 16; ++k) { int v = wsum[k]; wsum[k] = run; run += v; }
    }
    __syncthreads();
    int base = wsum[wid] + (sum - s);     // exclusive prefix for this thread
    int b0 = base, b1 = base + l0, b2 = b1 + l1, b3 = b2 + l2;
    cur[4 * t] = b0; cur[4 * t + 1] = b1; cur[4 * t + 2] = b2; cur[4 * t + 3] = b3;
    int* bsb = bstart + b * (NBKT + 1);
    bsb[4 * t] = b0; bsb[4 * t + 1] = b1; bsb[4 * t + 2] = b2; bsb[4 * t + 3] = b3;
    if (t == 1023) bsb[NBKT] = N_PTS;
    __syncthreads();

    // scatter (xx_np = bitwise-numpy |p|^2, no fma)
    float4* Sb = S + ((size_t)b << 13);
    int*    Ob = O + ((size_t)b << 13);
    #pragma unroll
    for (int u = 0; u < 8; ++u) {
        int dst = atomicAdd(&cur[bk[u]], 1);
        float xx = __fadd_rn(__fadd_rn(__fmul_rn(px[u], px[u]), __fmul_rn(py[u], py[u])),
                             __fmul_rn(pz[u], pz[u]));
        Sb[dst] = make_float4(px[u], py[u], pz[u], xx);
        Ob[dst] = (u << 10) + t;
    }
}

// ---------------------------------------------------------------------------
// Main (r5-proven, 94.8 us): 16 lanes/query, 8 queries/block. Table-lookup
// radius; 2x-unrolled (z,y)-window segment scan with per-row circular
// y-window; ballot-compact u64 keys; rank select; fp64 epilogue. Output is
// the exact top-30 for ANY r2 once cnt lands in [KNN, CAPG].
// ---------------------------------------------------------------------------
__global__ __launch_bounds__(BLOCK, 6) void knn_normal_kernel(const float4* __restrict__ S,
                                                              const int* __restrict__ O,
                                                              const int* __restrict__ bstart,
                                                              const float* __restrict__ R2T,
                                                              float* __restrict__ out) {
    __shared__ unsigned long long ldk[GROUPS * STR];

    const int t    = threadIdx.x;
    const int l16  = t & 15;
    const int g    = t >> 4;
    const int gsh  = (t & 63) & ~15;
    const int qblk = (blockIdx.x * 1031) & 4095;   // bijective swizzle: flatten tail
    const int qid  = qblk * GROUPS + g;
    const int b    = qid >> 13;
    const int pos  = qid & (N_PTS - 1);
    const float4* __restrict__ P  = S + ((size_t)b << 13);
    const int*    __restrict__ Ob = O + ((size_t)b << 13);
    const int*    __restrict__ bs = bstart + b * (NBKT + 1);
    const float4 qp = P[pos];
    const int    oi = Ob[pos];

    unsigned long long* __restrict__ ldg = ldk + g * STR;

    // ---- radius via host-built table (any r2 is output-correct; retries fix cnt)
    const int rbin = min((int)(qp.w * RSCALE), RBINS - 1);
    float r2 = R2T[rbin];

    int  cnt = 0;
    bool active = true;

    for (;;) {
        if (active) {
            cnt = 0;
            float w  = __fmaf_rn(sqrtf(r2), 1.002f, 1e-3f);   // guard band; w > sqrt(r2)
            float w2 = __fmul_rn(w, w);
            int zlo = clampi((int)floorf((qp.z - w - CLO) * CSC), 0, NZ - 1);
            int zhi = clampi((int)floorf((qp.z + w - CLO) * CSC), 0, NZ - 1);
            for (int zb = zlo; zb <= zhi; ++zb) {
                // lower bound on |pz - qz| for any point in this z-row (0.999 guard)
                float z0  = CLO + (float)zb * INVCSC;
                float dzr = fmaxf(fmaxf(z0 - qp.z, qp.z - (z0 + INVCSC)), 0.0f) * 0.999f;
                float hw2 = __fmaf_rn(-dzr, dzr, w2);
                if (hw2 <= 0.0f) continue;            // row provably hit-free
                float hw  = __fmaf_rn(sqrtf(hw2), 1.001f, 1e-4f);   // inflated upper bound
                int ylo = clampi((int)floorf((qp.y - hw - CLO) * CSC), 0, NY - 1);
                int yhi = clampi((int)floorf((qp.y + hw - CLO) * CSC), 0, NY - 1);
                int lo = bs[(zb << 6) + ylo];
                int hi = bs[(zb << 6) + yhi + 1];
                int smax = (hi - lo + 31) >> 5;   // group-uniform, 32 cand/iter
                for (int s = 0; s < smax; ++s) {
                    int j1  = lo + (s << 5) + l16;
                    int j2  = j1 + 16;
                    int jc1 = j1 < hi ? j1 : hi - 1;
                    int jc2 = j2 < hi ? j2 : hi - 1;
                    float4 p1 = P[jc1];
                    float4 p2 = P[jc2];
                    float mm1 = __fmaf_rn(qp.z, p1.z, __fmaf_rn(qp.y, p1.y, __fmul_rn(qp.x, p1.x)));
                    float d1  = __fsub_rn(__fadd_rn(qp.w, p1.w), __fmul_rn(2.0f, mm1));
                    float mm2 = __fmaf_rn(qp.z, p2.z, __fmaf_rn(qp.y, p2.y, __fmul_rn(qp.x, p2.x)));
                    float d2  = __fsub_rn(__fadd_rn(qp.w, p2.w), __fmul_rn(2.0f, mm2));
                    bool hit1 = (j1 < hi) && (d1 <= r2);
                    bool hit2 = (j2 < hi) && (d2 <= r2);
                    unsigned long long m1 = __ballot(hit1);
                    unsigned sub1 = (unsigned)((m1 >> gsh) & 0xFFFFull);
                    if (hit1) {
                        int slot = cnt + __popc(sub1 & ((1u << l16) - 1u));
                        if (slot < CAPG) {
                            unsigned u = __float_as_uint(d1);
                            u = (u & 0x80000000u) ? ~u : (u | 0x80000000u);
                            ldg[slot] = ((unsigned long long)u << 28) | (unsigned long long)jc1;
                        }
                    }
                    cnt += __popc(sub1);
                    unsigned long long m2 = __ballot(hit2);
                    unsigned sub2 = (unsigned)((m2 >> gsh) & 0xFFFFull);
                    if (hit2) {
                        int slot = cnt + __popc(sub2 & ((1u << l16) - 1u));
                        if (slot < CAPG) {
                            unsigned u = __float_as_uint(d2);
                            u = (u & 0x80000000u) ? ~u : (u | 0x80000000u);
                            ldg[slot] = ((unsigned long long)u << 28) | (unsigned long long)jc2;
                        }
                    }
                    cnt += __popc(sub2);
                }
            }
        }
        bool bad = active && (cnt < KNN || cnt > CAPG);
        if (__ballot(bad) == 0ULL) break;         // wave-uniform exit
        active = bad;
        if (active) r2 = (cnt < KNN) ? r2 * 1.6f : r2 * 0.82f;
    }

    // fill orig-idx field (bits 14..27) so u64 order == lex (d, orig idx)
    for (int k = l16; k < cnt; k += 16) {
        unsigned long long key = ldg[k];
        int jc = (int)(key & 0x3FFFull);
        ldg[k] = (key & ~0x0FFFFFFFull) | ((unsigned long long)Ob[jc] << 14) | (unsigned long long)jc;
    }
    __syncthreads();

    // ---- stable top-30: rank by u64 key (keys unique) ----
    const double qx = (double)qp.x, qy = (double)qp.y, qz = (double)qp.z;
    double sx = 0.0, sy = 0.0, sz = 0.0;
    double sxx = 0.0, sxy = 0.0, sxz = 0.0, syy = 0.0, syz = 0.0, szz = 0.0;

    for (int k = l16; k < cnt; k += 16) {
        unsigned long long key = ldg[k];
        int rank = 0;
        for (int u = 0; u < cnt; ++u) rank += (ldg[u] < key) ? 1 : 0;
        if (rank < KNN) {                         // exactly 30 survivors
            float4 p = P[(int)(key & 0x3FFFull)];
            double ax = (double)p.x - qx, ay = (double)p.y - qy, az = (double)p.z - qz;
            sx += ax; sy += ay; sz += az;
            sxx = fma(ax, ax, sxx); sxy = fma(ax, ay, sxy); sxz = fma(ax, az, sxz);
            syy = fma(ay, ay, syy); syz = fma(ay, az, syz); szz = fma(az, az, szz);
        }
    }

    #pragma unroll
    for (int off = 1; off < 16; off <<= 1) {
        sx  += __shfl_xor(sx,  off, 16); sy  += __shfl_xor(sy,  off, 16); sz  += __shfl_xor(sz,  off, 16);
        sxx += __shfl_xor(sxx, off, 16); sxy += __shfl_xor(sxy, off, 16); sxz += __shfl_xor(sxz, off, 16);
        syy += __shfl_xor(syy, off, 16); syz += __shfl_xor(syz, off, 16); szz += __shfl_xor(szz, off, 16);
    }

    if (l16 == 0) {
        const double kinv = 1.0 / (double)KNN;
        double m00 = sxx - sx * sx * kinv;
        double m11 = syy - sy * sy * kinv;
        double m22 = szz - sz * sz * kinv;
        double m01 = sxy - sx * sy * kinv;
        double m02 = sxz - sx * sz * kinv;
        double m12 = syz - sy * sz * kinv;

        double nx = 1.0, ny = 0.0, nz = 0.0;
        double q3 = (m00 + m11 + m22) / 3.0;
        double p1 = m01 * m01 + m02 * m02 + m12 * m12;
        double d00 = m00 - q3, d11 = m11 - q3, d22 = m22 - q3;
        double p2 = d00 * d00 + d11 * d11 + d22 * d22 + 2.0 * p1;
        if (p2 > 1e-280) {
            double pp = sqrt(p2 / 6.0);
            double ip = 1.0 / pp;
            double b00 = d00 * ip, b11 = d11 * ip, b22 = d22 * ip;
            double b01 = m01 * ip, b02 = m02 * ip, b12 = m12 * ip;
            double detB = b00 * (b11 * b22 - b12 * b12)
                        - b01 * (b01 * b22 - b12 * b02)
                        + b02 * (b01 * b12 - b11 * b02);
            double rr = 0.5 * detB;
            rr = rr < -1.0 ? -1.0 : (rr > 1.0 ? 1.0 : rr);
            double phi = acos(rr) / 3.0;
            double lam = q3 + 2.0 * pp * cos(phi + 2.0943951023931953); // smallest eig
            double a00 = m00 - lam, a11 = m11 - lam, a22 = m22 - lam;
            double v0x = m01 * m12 - m02 * a11, v0y = m02 * m01 - a00 * m12, v0z = a00 * a11 - m01 * m01;
            double v1x = m01 * a22 - m02 * m12, v1y = m02 * m02 - a00 * a22, v1z = a00 * m12 - m01 * m02;
            double v2x = a11 * a22 - m12 * m12, v2y = m12 * m02 - m01 * a22, v2z = m01 * m12 - a11 * m02;
            double n0 = v0x * v0x + v0y * v0y + v0z * v0z;
            double n1 = v1x * v1x + v1y * v1y + v1z * v1z;
            double n2 = v2x * v2x + v2y * v2y + v2z * v2z;
            double bx = v0x, by = v0y, bz = v0z, bn = n0;
            if (n1 > bn) { bx = v1x; by = v1y; bz = v1z; bn = n1; }
            if (n2 > bn) { bx = v2x; by = v2y; bz = v2z; bn = n2; }
            if (bn > 1e-280) {
                double inv = 1.0 / sqrt(bn);
                nx = bx * inv; ny = by * inv; nz = bz * inv;
            }
        }
        double dq = -(qx * nx + qy * ny + qz * nz);
        if (dq < 0.0) { nx = -nx; ny = -ny; nz = -nz; }

        float* ob = out + (size_t)b * 6 * N_PTS;
        ob[3 * N_PTS + oi] = (float)nx;
        ob[4 * N_PTS + oi] = (float)ny;
        ob[5 * N_PTS + oi] = (float)nz;
    }
}

// ---------------------------------------------------------------------------
// Host-side radius table: input-independent, computed once (double precision),
// async-copied to the workspace each launch (8 KB, graph-capturable).
// ---------------------------------------------------------------------------
static float  g_r2t[RBINS];
static bool   g_r2t_init = false;

static void build_r2t_host() {
    for (int k = 0; k < RBINS; ++k) {
        double wrep = ((double)k + 0.5) * ((double)RWMAX / (double)RBINS);
        double c = sqrt(wrep); if (c < 1e-3) c = 1e-3;
        double rlo = 0.05, rhi = 6.0;
        for (int it = 0; it < 40; ++it) {
            double r = 0.5 * (rlo + rhi);
            double slo = c - r; if (slo < 0.0) slo = 0.0;
            double h = (c + r - slo) * 0.125;
            double f = 0.0;
            for (int l = 0; l <= 8; ++l) {
                double sq = slo + h * (double)l;
                double cs = c - sq;
                double hh = (r * r - cs * cs) * (0.5 / c);
                double cap = 2.0 * sq;
                if (hh > cap) hh = cap;
                if (hh < 0.0) hh = 0.0;
                double wq = (l == 0 || l == 8) ? 1.0 : ((l & 1) ? 4.0 : 2.0);
                f += wq * exp(-0.5 * sq * sq) * sq * hh;
            }
            double lam = 1089.3 * f * h;       // 520.1 * 2*pi / 3
            if (lam < (double)LAMBDA) rlo = r; else rhi = r;
        }
        double rad = rhi * 1.02;
        g_r2t[k] = (float)(rad * rad);
    }
}

// ---------------------------------------------------------------------------
extern "C" void kernel_launch(void* const* d_in, const int* in_sizes, int n_in,
                              void* d_out, int out_size, void* d_ws, size_t ws_size,
                              hipStream_t stream) {
    const float* x = (const float*)d_in[0];
    float* out = (float*)d_out;
    char* ws = (char*)d_ws;
    float4* S    = (float4*)(ws);                 // 512 KB
    int*    O    = (int*)(ws + 524288);           // 128 KB
    int*    bsta = (int*)(ws + 655360);           // 65552 B
    float*  r2t  = (float*)(ws + 720912);         // 8 KB

    if (!g_r2t_init) { build_r2t_host(); g_r2t_init = true; }
    hipMemcpyAsync(r2t, g_r2t, RBINS * sizeof(float), hipMemcpyHostToDevice, stream);

    prep_kernel<<<dim3(4), dim3(1024), 0, stream>>>(x, S, O, bsta, out);
    knn_normal_kernel<<<dim3(32768 / GROUPS), dim3(BLOCK), 0, stream>>>(S, O, bsta, r2t, out);
}